// Round 16
// baseline (708.487 us; speedup 1.0000x reference)
//
#include <hip/hip_runtime.h>
#include <hip/hip_bf16.h>
#include <cstdint>

typedef __attribute__((ext_vector_type(8))) short short8;
typedef __attribute__((ext_vector_type(4))) float f32x4;

#define EPSV 1e-5f

// async global->LDS, 16B per lane; LDS dest = wave-uniform base + lane*16
__device__ __forceinline__ void gload_lds16(const void* g, void* l) {
  __builtin_amdgcn_global_load_lds(
      (const __attribute__((address_space(1))) void*)(uintptr_t)g,
      (__attribute__((address_space(3))) void*)(uint32_t)(uintptr_t)l,
      16, 0, 0);
}

__device__ __forceinline__ uint32_t f2bf_rne(float v) {
  const uint32_t u = __float_as_uint(v);
  const uint32_t r = ((u >> 16) & 1u) + 0x7fffu;
  return (u + r) >> 16;
}
__device__ __forceinline__ float bf2f(uint32_t u) {
  return __uint_as_float(u << 16);
}

// ---------------- spatial mean (attr): one block per channel ----------------
__global__ void mean_kernel(const float* __restrict__ in, float* __restrict__ out,
                            int HW, float inv) {
  const int ch = blockIdx.x;
  const int t = threadIdx.x;
  const float* p = in + (size_t)ch * HW;
  float s = 0.f;
  const int nv = HW >> 2;
  const float4* pv = (const float4*)p;
  for (int i = t; i < nv; i += 256) { float4 v = pv[i]; s += v.x + v.y + v.z + v.w; }
  __shared__ float red[256];
  red[t] = s; __syncthreads();
  for (int off = 128; off > 0; off >>= 1) {
    if (t < off) red[t] += red[t + off];
    __syncthreads();
  }
  if (t == 0) out[ch] = red[0] * inv;
}

// ---- fused feat means: all 5 scales in one launch (2560 blocks) ----
__global__ void meanf_kernel(const float* __restrict__ f0, const float* __restrict__ f1,
                             const float* __restrict__ f2, const float* __restrict__ f3,
                             const float* __restrict__ f4, float* __restrict__ out) {
  const int scale = blockIdx.x >> 9;
  const int ch = blockIdx.x & 511;
  const int t = threadIdx.x;
  const float* base;
  int HW;
  switch (scale) {
    case 0: base = f0; HW = 16384; break;
    case 1: base = f1; HW = 4096;  break;
    case 2: base = f2; HW = 1024;  break;
    case 3: base = f3; HW = 256;   break;
    default: base = f4; HW = 64;   break;
  }
  const float* p = base + (size_t)ch * HW;
  float s = 0.f;
  const int nv = HW >> 2;
  const float4* pv = (const float4*)p;
  for (int i = t; i < nv; i += 256) { float4 v = pv[i]; s += v.x + v.y + v.z + v.w; }
  __shared__ float red[256];
  red[t] = s; __syncthreads();
  for (int off = 128; off > 0; off >>= 1) {
    if (t < off) red[t] += red[t + off];
    __syncthreads();
  }
  if (t == 0) out[scale * 512 + ch] = red[0] / (float)HW;
}

// ------- fold BN into weights for ONE scale; layout [g][tap][co][ci] bf16 ----
__global__ void wtrans_kernel(const float* __restrict__ cw,
                              const float* __restrict__ gamma, const float* __restrict__ beta,
                              const float* __restrict__ mean, const float* __restrict__ var,
                              __hip_bfloat16* __restrict__ wt, float* __restrict__ bias,
                              int i) {
  __shared__ float wl[2304];
  const int oc = blockIdx.x;   // 0..2047
  const int t  = threadIdx.x;  // 0..255
  const int idx = i * 2048 + oc;
  const float* src = cw + (size_t)idx * 2304;
  for (int e = t; e < 2304; e += 256) wl[e] = src[e];
  __syncthreads();
  const float sc = rsqrtf(var[idx] + EPSV) * gamma[idx];
  if (t == 0) bias[idx] = beta[idx] - mean[idx] * sc;
  const int g = oc >> 8, co = oc & 255;
  const size_t dbase = (size_t)g * 9 * 65536 + co * 256 + t;
#pragma unroll
  for (int tap = 0; tap < 9; ++tap)
    wt[dbase + (size_t)tap * 65536] = __float2bfloat16(wl[t * 9 + tap] * sc);
}

// ------------- gating: MLPs + logits + softmax (1 block) -------------
__global__ void gate_kernel(const float* __restrict__ meanA, const float* __restrict__ meanF,
                            const float* __restrict__ Wa, const float* __restrict__ ba,
                            const float* __restrict__ Wf, const float* __restrict__ bfp,
                            float* __restrict__ attn) {
  __shared__ float mA[16 * 256];
  __shared__ float mF[10 * 256];
  __shared__ float pA[16 * 256];
  __shared__ float pF[10 * 256];
  __shared__ float lg[80];
  const int t = threadIdx.x;
  for (int i = t; i < 4096; i += 256) mA[i] = meanA[i];
  for (int i = t; i < 2560; i += 256) mF[i] = meanF[i];
  __syncthreads();
  {
    float acc[16];
#pragma unroll
    for (int j = 0; j < 16; ++j) acc[j] = 0.f;
    for (int ci = 0; ci < 256; ++ci) {
      const float w = Wa[t * 256 + ci];
#pragma unroll
      for (int j = 0; j < 16; ++j) acc[j] += mA[j * 256 + ci] * w;
    }
    const float bb = ba[t];
#pragma unroll
    for (int j = 0; j < 16; ++j) pA[j * 256 + t] = acc[j] + bb;
  }
  {
    float acc[10];
#pragma unroll
    for (int j = 0; j < 10; ++j) acc[j] = 0.f;
    for (int ci = 0; ci < 256; ++ci) {
      const float w = Wf[t * 256 + ci];
#pragma unroll
      for (int j = 0; j < 10; ++j) acc[j] += mF[j * 256 + ci] * w;
    }
    const float bb = bfp[t];
#pragma unroll
    for (int j = 0; j < 10; ++j) pF[j * 256 + t] = acc[j] + bb;
  }
  __syncthreads();
  if (t < 80) {
    const int i = t >> 4, r = t & 15, b = r >> 3, k = r & 7;
    const float* a = &pA[(b * 8 + k) * 256];
    const float* f = &pF[(i * 2 + b) * 256];
    float d = 0.f;
    for (int c = 0; c < 256; ++c) d += a[c] * f[c];
    lg[t] = d;
  }
  __syncthreads();
  if (t < 10) {
    const int base = t * 8;
    float m = lg[base];
    for (int k = 1; k < 8; ++k) m = fmaxf(m, lg[base + k]);
    float e[8], s = 0.f;
    for (int k = 0; k < 8; ++k) { e[k] = __expf(lg[base + k] - m); s += e[k]; }
    const float invs = 1.f / s;
    for (int k = 0; k < 8; ++k) attn[base + k] = e[k] * invs;
  }
}

// --- bilinear resize (align_corners) NCHW f32 -> padded NHWC bf16 ----
// Used for scale 1 (scl=1.0 -> exact bf16 NHWC conversion) and fallback path.
__global__ void resize_kernel(const float* __restrict__ attr,
                              __hip_bfloat16* __restrict__ R,
                              int W, int Hp, int Wp, float scl) {
  const int bk = blockIdx.x;   // bb*8+k
  const int yp = blockIdx.y;
  const int t  = threadIdx.x;
  const size_t rowbase = ((size_t)bk * Hp + yp) * (size_t)Wp * 256;
  if (yp == 0 || yp == Hp - 1) {
    uint32_t* p = (uint32_t*)(R + rowbase);
    const int n = Wp * 128;
    for (int idx = t; idx < n; idx += 256) p[idx] = 0u;
    return;
  }
  const int y = yp - 1;
  const float fy = y * scl;
  int y0 = (int)floorf(fy); if (y0 > 63) y0 = 63;
  const float wy = fy - (float)y0;
  const int y1 = min(y0 + 1, 63);
  __shared__ float buf[2][64][65];
  const int cc = t >> 2, seg = (t & 3) * 16;
  const int bb = bk >> 3, k = bk & 7;
  const float* ab = attr + (size_t)bb * 2048 * 4096;
  const int ci = t & 63;
  for (int cq = 0; cq < 4; ++cq) {
    __syncthreads();
    {
      const int ch = k * 256 + cq * 64 + cc;
      const float* r0 = ab + ((size_t)ch * 64 + y0) * 64;
      const float* r1 = ab + ((size_t)ch * 64 + y1) * 64;
#pragma unroll
      for (int u = 0; u < 4; ++u) {
        float4 v0 = ((const float4*)r0)[(t & 3) * 4 + u];
        float4 v1 = ((const float4*)r1)[(t & 3) * 4 + u];
        buf[0][cc][seg + u * 4 + 0] = v0.x; buf[0][cc][seg + u * 4 + 1] = v0.y;
        buf[0][cc][seg + u * 4 + 2] = v0.z; buf[0][cc][seg + u * 4 + 3] = v0.w;
        buf[1][cc][seg + u * 4 + 0] = v1.x; buf[1][cc][seg + u * 4 + 1] = v1.y;
        buf[1][cc][seg + u * 4 + 2] = v1.z; buf[1][cc][seg + u * 4 + 3] = v1.w;
      }
    }
    __syncthreads();
    for (int x = t >> 6; x < W; x += 4) {
      const float fx = x * scl;
      int x0 = (int)floorf(fx); if (x0 > 63) x0 = 63;
      const float wx = fx - (float)x0;
      const int x1 = min(x0 + 1, 63);
      const float top = buf[0][ci][x0] * (1.f - wx) + buf[0][ci][x1] * wx;
      const float bot = buf[1][ci][x0] * (1.f - wx) + buf[1][ci][x1] * wx;
      R[rowbase + (size_t)(x + 1) * 256 + cq * 64 + ci] = __float2bfloat16(top * (1.f - wy) + bot * wy);
    }
    if (t < 64) {
      R[rowbase + cq * 64 + t] = __float2bfloat16(0.f);
      R[rowbase + (size_t)(Wp - 1) * 256 + cq * 64 + t] = __float2bfloat16(0.f);
    }
  }
}

// ---- bilinear resize from R1 (scale-1 identity buffer, NHWC bf16 66x66 padded)
__global__ void resizeR1_kernel(const __hip_bfloat16* __restrict__ R1,
                                __hip_bfloat16* __restrict__ R,
                                int W, int Hp, int Wp, float scl) {
  const int bk = blockIdx.x;   // 0..15
  const int yp = blockIdx.y;
  const int t  = threadIdx.x;
  const size_t rowbase = ((size_t)bk * Hp + yp) * (size_t)Wp * 256;
  if (yp == 0 || yp == Hp - 1) {
    uint32_t* p = (uint32_t*)(R + rowbase);
    const int n = Wp * 128;
    for (int idx = t; idx < n; idx += 256) p[idx] = 0u;
    return;
  }
  const int y = yp - 1;
  const float fy = y * scl;
  int y0 = (int)floorf(fy); if (y0 > 63) y0 = 63;
  const float wy = fy - (float)y0;
  const int y1 = min(y0 + 1, 63);
  const __hip_bfloat16* r0 = R1 + ((size_t)bk * 66 + (y0 + 1)) * 66 * 256 + 256;
  const __hip_bfloat16* r1 = R1 + ((size_t)bk * 66 + (y1 + 1)) * 66 * 256 + 256;
  const int ci4 = (t & 63) * 4;
  for (int x = t >> 6; x < W; x += 4) {
    const float fx = x * scl;
    int x0 = (int)floorf(fx); if (x0 > 63) x0 = 63;
    const float wx = fx - (float)x0;
    const int x1 = min(x0 + 1, 63);
    const ushort4 a00 = *(const ushort4*)&r0[x0 * 256 + ci4];
    const ushort4 a01 = *(const ushort4*)&r0[x1 * 256 + ci4];
    const ushort4 a10 = *(const ushort4*)&r1[x0 * 256 + ci4];
    const ushort4 a11 = *(const ushort4*)&r1[x1 * 256 + ci4];
    short4 st;
    {
      const float t0 = bf2f(a00.x) * (1.f - wx) + bf2f(a01.x) * wx;
      const float b0 = bf2f(a10.x) * (1.f - wx) + bf2f(a11.x) * wx;
      st.x = (short)f2bf_rne(t0 * (1.f - wy) + b0 * wy);
      const float t1 = bf2f(a00.y) * (1.f - wx) + bf2f(a01.y) * wx;
      const float b1 = bf2f(a10.y) * (1.f - wx) + bf2f(a11.y) * wx;
      st.y = (short)f2bf_rne(t1 * (1.f - wy) + b1 * wy);
      const float t2 = bf2f(a00.z) * (1.f - wx) + bf2f(a01.z) * wx;
      const float b2 = bf2f(a10.z) * (1.f - wx) + bf2f(a11.z) * wx;
      st.z = (short)f2bf_rne(t2 * (1.f - wy) + b2 * wy);
      const float t3 = bf2f(a00.w) * (1.f - wx) + bf2f(a01.w) * wx;
      const float b3 = bf2f(a10.w) * (1.f - wx) + bf2f(a11.w) * wx;
      st.w = (short)f2bf_rne(t3 * (1.f - wy) + b3 * wy);
    }
    *(short4*)&R[rowbase + (size_t)(x + 1) * 256 + ci4] = st;
  }
  if (t < 64) {
    const short4 z4 = {0, 0, 0, 0};
    *(short4*)&R[rowbase + t * 4] = z4;
    *(short4*)&R[rowbase + (size_t)(Wp - 1) * 256 + t * 4] = z4;
  }
}

// stage index -> (g, ty, tx, cq)
__device__ __forceinline__ void coords36(int u, int g0, int& g, int& ty, int& tx, int& cq) {
  g = g0 + u / 36;
  const int r = u % 36;
  const int tap = r >> 2;
  cq = r & 3;
  ty = tap / 3;
  tx = tap - ty * 3;
}

// ===== conv256 v5: 256x256, 8 waves, 2-barrier FREE-REGION K-loop =====
// Per K-tile: {issue t+1 (8 gload_lds), vmcnt(8), barrier, <free region:
// 24 ds_read_b128 + 64 MFMA, compiler-scheduled partial lgkmcnt interleave>,
// barrier}. No sched_barrier/setprio/inner barriers -> hipcc streams LDS
// reads under the MFMA cluster (m97 behavior) while counted vmcnt keeps the
// global prefetch in flight across barriers.
__global__ __launch_bounds__(512, 1)
void conv256_kernel(const __hip_bfloat16* __restrict__ R,
                    const __hip_bfloat16* __restrict__ Wt,   // [8][9][256][256]
                    const float* __restrict__ bias,          // [2048] this scale
                    const float* __restrict__ attn,          // [2][8] this scale
                    __hip_bfloat16* __restrict__ zout,
                    int W, int lw, int Hp, int Wp, int HW,
                    int NB, int gcount) {
  __shared__ alignas(16) __hip_bfloat16 ldsA[2][256 * 64];
  __shared__ alignas(16) __hip_bfloat16 ldsB[2][256 * 64];
  const int tid  = threadIdx.x;
  const int lane = tid & 63;
  const int wave = __builtin_amdgcn_readfirstlane(tid >> 6);
  const int wm = (wave >> 2) * 128;
  const int wn = (wave & 3) * 64;

  const int X = gridDim.x;
  int xp = blockIdx.x, yv = blockIdx.y;
  if (X * gridDim.y == 256) {
    const int lin2 = blockIdx.x + X * blockIdx.y;
    const int d = (lin2 & 7) * 32 + (lin2 >> 3);
    yv = d / X; xp = d - yv * X;
  }
  const int n0 = xp * 256;
  const int bb = yv % NB;
  const int gs = yv / NB;
  const int g0 = gs * gcount;

  const int c8 = lane & 7, r8 = lane >> 3;
  const int sc = (c8 ^ r8) << 3;
  const int aoff0 = ((wave * 32 + r8) << 8) + sc;
  const int dst0  = wave * 2048;
  int boff[4];
#pragma unroll
  for (int q = 0; q < 4; ++q) {
    const int row = wave * 32 + q * 8 + r8;
    const int sg = n0 + row;
    const int y = sg >> lw, x = sg & (W - 1);
    boff[q] = ((y * Wp + x) << 8) + sc;
  }

  const size_t rgstride = (size_t)Hp * Wp * 256;
  const __hip_bfloat16* Rb = R + (size_t)bb * 8 * rgstride;

  const f32x4 fz = {0.f, 0.f, 0.f, 0.f};
  f32x4 acc[8][4];
  uint32_t finp[8][4][2];
#pragma unroll
  for (int mf = 0; mf < 8; ++mf)
#pragma unroll
    for (int nf = 0; nf < 4; ++nf) {
      acc[mf][nf] = fz; finp[mf][nf][0] = 0u; finp[mf][nf][1] = 0u;
    }

  const int nk = gcount * 36;

#define ISSUE_KT(t_)                                                           \
  {                                                                            \
    int g_, ty_, tx_, cq_;                                                     \
    coords36((t_), g0, g_, ty_, tx_, cq_);                                     \
    const __hip_bfloat16* wp = Wt + (((size_t)g_ * 9 + ty_ * 3 + tx_) << 16) + \
                               (cq_ << 6);                                     \
    const __hip_bfloat16* rp = Rb + (size_t)g_ * rgstride +                    \
                               ((ty_ * Wp + tx_) << 8) + (cq_ << 6);           \
    const int sl_ = (t_) & 1;                                                  \
    _Pragma("unroll")                                                          \
    for (int q = 0; q < 4; ++q) {                                              \
      gload_lds16(wp + aoff0 + q * 2048, &ldsA[sl_][dst0 + q * 512]);          \
      gload_lds16(rp + boff[q], &ldsB[sl_][dst0 + q * 512]);                   \
    }                                                                          \
  }

  ISSUE_KT(0);

  int foldc = 0, gcur = g0;
  for (int t = 0; t < nk; ++t) {
    if (t + 1 < nk) {
      ISSUE_KT(t + 1);
      asm volatile("s_waitcnt vmcnt(8)" ::: "memory");   // tile t landed; t+1 in flight
    } else {
      asm volatile("s_waitcnt vmcnt(0)" ::: "memory");
    }
    __builtin_amdgcn_s_barrier();          // slot t visible to all waves
    asm volatile("" ::: "memory");

    const int c = t & 1;
    const __hip_bfloat16* pA = &ldsA[c][0];
    const __hip_bfloat16* pB = &ldsB[c][0];

    // ---- free region: compiler interleaves reads with MFMAs ----
#pragma unroll
    for (int ks = 0; ks < 2; ++ks) {
      const int cb = ks * 4 + (lane >> 4);
      short8 bfv[4];
#pragma unroll
      for (int nf = 0; nf < 4; ++nf) {
        const int row = wn + nf * 16 + (lane & 15);
        bfv[nf] = *(const short8*)&pB[(row << 6) + ((cb ^ (row & 7)) << 3)];
      }
#pragma unroll
      for (int h = 0; h < 2; ++h) {
        short8 af[4];
#pragma unroll
        for (int m = 0; m < 4; ++m) {
          const int row = wm + (h * 4 + m) * 16 + (lane & 15);
          af[m] = *(const short8*)&pA[(row << 6) + ((cb ^ (row & 7)) << 3)];
        }
#pragma unroll
        for (int m = 0; m < 4; ++m)
#pragma unroll
          for (int nf = 0; nf < 4; ++nf)
            acc[h * 4 + m][nf] = __builtin_amdgcn_mfma_f32_16x16x32_bf16(
                af[m], bfv[nf], acc[h * 4 + m][nf], 0, 0, 0);
      }
    }

    if (++foldc == 36) {                   // group done: fold relu+attn into packed fin
      foldc = 0;
      const float aw = attn[bb * 8 + gcur];
#pragma unroll
      for (int mf = 0; mf < 8; ++mf) {
        const int cobase = wm + mf * 16 + ((lane >> 4) << 2);
#pragma unroll
        for (int pr = 0; pr < 2; ++pr) {
          const float b0v = bias[(gcur << 8) + cobase + pr * 2 + 0];
          const float b1v = bias[(gcur << 8) + cobase + pr * 2 + 1];
#pragma unroll
          for (int nf = 0; nf < 4; ++nf) {
            const uint32_t p = finp[mf][nf][pr];
            const float f0 = __uint_as_float(p << 16)
                           + aw * fmaxf(acc[mf][nf][pr * 2 + 0] + b0v, 0.f);
            const float f1 = __uint_as_float(p & 0xffff0000u)
                           + aw * fmaxf(acc[mf][nf][pr * 2 + 1] + b1v, 0.f);
            finp[mf][nf][pr] = (f2bf_rne(f1) << 16) | f2bf_rne(f0);
          }
        }
#pragma unroll
        for (int nf = 0; nf < 4; ++nf) acc[mf][nf] = fz;
      }
      ++gcur;
    }
    __builtin_amdgcn_s_barrier();          // all waves done reading slot t (WAR)
    asm volatile("" ::: "memory");
  }
#undef ISSUE_KT

  __hip_bfloat16* zb = zout + (size_t)(gs * 2 + bb) * 256 * (size_t)HW;
#pragma unroll
  for (int mf = 0; mf < 8; ++mf) {
    const int cobase = wm + mf * 16 + ((lane >> 4) << 2);
#pragma unroll
    for (int nf = 0; nf < 4; ++nf) {
      const int n = n0 + wn + nf * 16 + (lane & 15);
#pragma unroll
      for (int pr = 0; pr < 2; ++pr) {
        const uint32_t p = finp[mf][nf][pr];
        zb[(size_t)(cobase + pr * 2 + 0) * HW + n] =
            __float2bfloat16(__uint_as_float(p << 16));
        zb[(size_t)(cobase + pr * 2 + 1) * HW + n] =
            __float2bfloat16(__uint_as_float(p & 0xffff0000u));
      }
    }
  }
}

// -------- 128x128 conv (scales 2-4 + fallback), R15 unchanged ---------
__global__ __launch_bounds__(256, 2)
void conv_kernel(const __hip_bfloat16* __restrict__ R,
                 const __hip_bfloat16* __restrict__ Wt,
                 const float* __restrict__ bias,
                 const float* __restrict__ attn,
                 const float* __restrict__ featp,
                 void* __restrict__ outp,
                 int W, int lw, int Hp, int Wp, int HW,
                 int b0, int NB, int gcount) {
  __shared__ alignas(16) __hip_bfloat16 ldsA[2][128 * 64];
  __shared__ alignas(16) __hip_bfloat16 ldsB[3][128 * 64];
  const int tid  = threadIdx.x;
  const int lane = tid & 63;
  const int wave = __builtin_amdgcn_readfirstlane(tid >> 6);
  const int wm = (wave >> 1) * 64;
  const int wn = (wave & 1) * 64;

  const int nx  = gridDim.x;
  const int lin = blockIdx.x;
  const int pos = ((nx & 7) == 0) ? ((lin & 7) * (nx >> 3) + (lin >> 3)) : lin;
  const int co0 = (pos & 1) * 128;
  const int n0  = (pos >> 1) * 128;

  const int bb  = (int)blockIdx.y % NB;
  const int gs  = (int)blockIdx.y / NB;
  const int b   = b0 + bb;
  const int g0  = gs * gcount;

  const int c8 = lane & 7;
  const int r8 = lane >> 3;
  int aoff[4], boff[4], dst[4];
#pragma unroll
  for (int q = 0; q < 4; ++q) {
    const int row = (wave * 4 + q) * 8 + r8;
    const int sc = (c8 ^ (row & 7)) << 3;
    aoff[q] = ((co0 + row) << 8) + sc;
    int sg = n0 + row; if (sg >= HW) sg = HW - 1;
    const int y = sg >> lw, x = sg & (W - 1);
    boff[q] = ((y * Wp + x) << 8) + sc;
    dst[q] = (wave * 4 + q) * 512;
  }

  const size_t rgstride = (size_t)Hp * Wp * 256;
  const __hip_bfloat16* Rb = R + (size_t)bb * 8 * rgstride;

  const f32x4 fz = {0.f, 0.f, 0.f, 0.f};
  f32x4 fin[4][4], acc[4][4];
#pragma unroll
  for (int mf = 0; mf < 4; ++mf)
#pragma unroll
    for (int nf = 0; nf < 4; ++nf) { fin[mf][nf] = fz; acc[mf][nf] = fz; }

  const int nstages = gcount * 36;
  {
    int g, ty, tx, cq;
    coords36(0, g0, g, ty, tx, cq);
    const __hip_bfloat16* wp = Wt + (((size_t)g * 9 + ty * 3 + tx) << 16) + (cq << 6);
    const __hip_bfloat16* rp = Rb + (size_t)g * rgstride + ((ty * Wp + tx) << 8) + (cq << 6);
#pragma unroll
    for (int q = 0; q < 4; ++q) gload_lds16(wp + aoff[q], &ldsA[0][dst[q]]);
#pragma unroll
    for (int q = 0; q < 4; ++q) gload_lds16(rp + boff[q], &ldsB[0][dst[q]]);
    coords36(1 < nstages ? 1 : 0, g0, g, ty, tx, cq);
    const __hip_bfloat16* rp1 = Rb + (size_t)g * rgstride + ((ty * Wp + tx) << 8) + (cq << 6);
#pragma unroll
    for (int q = 0; q < 4; ++q) gload_lds16(rp1 + boff[q], &ldsB[1][dst[q]]);
  }

  int bcur = 0, b2 = 2;
  int foldc = 0, gcur = g0;

  for (int s = 0; s < nstages; ++s) {
    __builtin_amdgcn_s_barrier();
    asm volatile("" ::: "memory");
    if (s + 1 < nstages) {
      int g, ty, tx, cq;
      coords36(s + 1, g0, g, ty, tx, cq);
      const __hip_bfloat16* wp = Wt + (((size_t)g * 9 + ty * 3 + tx) << 16) + (cq << 6);
      __hip_bfloat16* dA = &ldsA[(s + 1) & 1][0];
#pragma unroll
      for (int q = 0; q < 4; ++q) gload_lds16(wp + aoff[q], dA + dst[q]);
    }
    if (s + 2 < nstages) {
      int g, ty, tx, cq;
      coords36(s + 2, g0, g, ty, tx, cq);
      const __hip_bfloat16* rp = Rb + (size_t)g * rgstride + ((ty * Wp + tx) << 8) + (cq << 6);
      __hip_bfloat16* dB = &ldsB[b2][0];
#pragma unroll
      for (int q = 0; q < 4; ++q) gload_lds16(rp + boff[q], dB + dst[q]);
    }
    if (s + 2 < nstages)      asm volatile("s_waitcnt vmcnt(12)" ::: "memory");
    else if (s + 1 < nstages) asm volatile("s_waitcnt vmcnt(8)" ::: "memory");
    else                      asm volatile("s_waitcnt vmcnt(0)" ::: "memory");
    __builtin_amdgcn_s_barrier();
    asm volatile("" ::: "memory");

    const __hip_bfloat16* pA = &ldsA[s & 1][0];
    const __hip_bfloat16* pB = &ldsB[bcur][0];
#pragma unroll
    for (int ks = 0; ks < 2; ++ks) {
      short8 af[4], bfv[4];
      const int cb = ks * 4 + (lane >> 4);
#pragma unroll
      for (int mf = 0; mf < 4; ++mf) {
        const int row = wm + mf * 16 + (lane & 15);
        af[mf] = *(const short8*)&pA[(row << 6) + ((cb ^ (row & 7)) << 3)];
      }
#pragma unroll
      for (int nf = 0; nf < 4; ++nf) {
        const int row = wn + nf * 16 + (lane & 15);
        bfv[nf] = *(const short8*)&pB[(row << 6) + ((cb ^ (row & 7)) << 3)];
      }
#pragma unroll
      for (int mf = 0; mf < 4; ++mf)
#pragma unroll
        for (int nf = 0; nf < 4; ++nf)
          acc[mf][nf] = __builtin_amdgcn_mfma_f32_16x16x32_bf16(
              af[mf], bfv[nf], acc[mf][nf], 0, 0, 0);
    }

    if (++bcur == 3) bcur = 0;
    if (++b2 == 3) b2 = 0;

    if (++foldc == 36) {
      foldc = 0;
      const float aw = attn[b * 8 + gcur];
#pragma unroll
      for (int mf = 0; mf < 4; ++mf) {
        const int cobase = co0 + wm + mf * 16 + ((lane >> 4) << 2);
#pragma unroll
        for (int r = 0; r < 4; ++r) {
          const float bs = bias[(gcur << 8) + cobase + r];
#pragma unroll
          for (int nf = 0; nf < 4; ++nf) {
            fin[mf][nf][r] += aw * fmaxf(acc[mf][nf][r] + bs, 0.f);
            acc[mf][nf][r] = 0.f;
          }
        }
      }
      ++gcur;
    }
  }

  const size_t plane = (size_t)256 * HW;
  if (featp) {
    const float* fb = featp + (size_t)b * plane;
    float* ob = (float*)outp + (size_t)b * plane;
#pragma unroll
    for (int mf = 0; mf < 4; ++mf) {
      const int cobase = co0 + wm + mf * 16 + ((lane >> 4) << 2);
#pragma unroll
      for (int nf = 0; nf < 4; ++nf) {
        const int n = n0 + wn + nf * 16 + (lane & 15);
        if (n < HW) {
#pragma unroll
          for (int r = 0; r < 4; ++r) {
            const size_t idx = (size_t)(cobase + r) * HW + n;
            ob[idx] = fmaxf(fb[idx] + fin[mf][nf][r], 0.f);
          }
        }
      }
    }
  } else {
    __hip_bfloat16* zb = (__hip_bfloat16*)outp + ((size_t)gs * 2 + b) * plane;
#pragma unroll
    for (int mf = 0; mf < 4; ++mf) {
      const int cobase = co0 + wm + mf * 16 + ((lane >> 4) << 2);
#pragma unroll
      for (int nf = 0; nf < 4; ++nf) {
        const int n = n0 + wn + nf * 16 + (lane & 15);
        if (n < HW) {
#pragma unroll
          for (int r = 0; r < 4; ++r)
            zb[(size_t)(cobase + r) * HW + n] = __float2bfloat16(fin[mf][nf][r]);
        }
      }
    }
  }
}

// ---- combine bf16 partials: out = relu(feat + sum_s z[s]) ----
__global__ void reduce_kernel(const __hip_bfloat16* __restrict__ z,
                              const float* __restrict__ feat,
                              float* __restrict__ outp, int total, int S) {
  const int i4 = (blockIdx.x * 256 + threadIdx.x) * 4;
  if (i4 >= total) return;
  float4 f = *(const float4*)(feat + i4);
  float s0 = f.x, s1 = f.y, s2 = f.z, s3 = f.w;
  for (int j = 0; j < S; ++j) {
    const ushort4 v = *(const ushort4*)(z + (size_t)j * total + i4);
    s0 += bf2f(v.x);
    s1 += bf2f(v.y);
    s2 += bf2f(v.z);
    s3 += bf2f(v.w);
  }
  float4 o = {fmaxf(s0, 0.f), fmaxf(s1, 0.f), fmaxf(s2, 0.f), fmaxf(s3, 0.f)};
  *(float4*)(outp + i4) = o;
}

extern "C" void kernel_launch(void* const* d_in, const int* in_sizes, int n_in,
                              void* d_out, int out_size, void* d_ws, size_t ws_size,
                              hipStream_t stream) {
  const float* feat[5];
  for (int i = 0; i < 5; ++i) feat[i] = (const float*)d_in[i];
  const float* attr = (const float*)d_in[5];
  const float* mfw = (const float*)d_in[6];
  const float* mfb = (const float*)d_in[7];
  const float* maw = (const float*)d_in[8];
  const float* mab = (const float*)d_in[9];
  const float* cw  = (const float*)d_in[10];
  const float* bng = (const float*)d_in[11];
  const float* bnb = (const float*)d_in[12];
  const float* bnm = (const float*)d_in[13];
  const float* bnv = (const float*)d_in[14];
  float* out = (float*)d_out;

  char* ws = (char*)d_ws;
  float* attnW = (float*)(ws);
  float* meanA = (float*)(ws + 512);
  float* meanF = (float*)(ws + 20480);
  float* biasW = (float*)(ws + 32768);
  __hip_bfloat16* Wt  = (__hip_bfloat16*)(ws + 131072);
  __hip_bfloat16* R1  = (__hip_bfloat16*)(ws + 9568256);
  __hip_bfloat16* R0  = (__hip_bfloat16*)(ws + 45252608);
  __hip_bfloat16* zbuf = (__hip_bfloat16*)(ws + 183697408);

  const bool full = ws_size >= (size_t)217251840;

  static const int HS[5] = {128, 64, 32, 16, 8};
  static const size_t OOFF[5] = {0, 8388608, 10485760, 11010048, 11141120};
  static const int ORDER[5] = {1, 0, 2, 3, 4};

  mean_kernel<<<4096, 256, 0, stream>>>(attr, meanA, 4096, 1.f / 4096.f);
  meanf_kernel<<<2560, 256, 0, stream>>>(feat[0], feat[1], feat[2], feat[3], feat[4], meanF);
  gate_kernel<<<1, 256, 0, stream>>>(meanA, meanF, maw, mab, mfw, mfb, attnW);

  if (full) {
    for (int oi = 0; oi < 5; ++oi) {
      const int i = ORDER[oi];
      const int H = HS[i], W = H, HW = H * W, Hp = H + 2, Wp = W + 2;
      const int lw = 31 - __builtin_clz((unsigned)W);
      const float scl = 63.f / (float)(H - 1);
      __hip_bfloat16* Ri = (i == 1) ? R1 : R0;

      wtrans_kernel<<<2048, 256, 0, stream>>>(cw, bng, bnb, bnm, bnv, Wt, biasW, i);
      if (i == 1)
        resize_kernel<<<dim3(16, Hp), 256, 0, stream>>>(attr, R1, W, Hp, Wp, scl);
      else
        resizeR1_kernel<<<dim3(16, Hp), 256, 0, stream>>>(R1, Ri, W, Hp, Wp, scl);

      if (i <= 1) {
        const int S = (i == 0) ? 2 : 8;
        const int gcount = 8 / S;
        conv256_kernel<<<dim3(HW / 256, 2 * S), 512, 0, stream>>>(
            Ri, Wt, biasW + i * 2048, attnW + i * 16,
            zbuf, W, lw, Hp, Wp, HW, 2, gcount);
        const int total = 2 * 256 * HW;
        reduce_kernel<<<(total / 4 + 255) / 256, 256, 0, stream>>>(
            zbuf, feat[i], out + OOFF[i], total, S);
      } else {
        const int ntiles = (HW + 127) / 128;
        conv_kernel<<<dim3(ntiles * 2, 16), 256, 0, stream>>>(
            Ri, Wt, biasW + i * 2048, attnW + i * 16,
            nullptr, zbuf, W, lw, Hp, Wp, HW, 0, 2, 1);
        const int total = 2 * 256 * HW;
        reduce_kernel<<<(total / 4 + 255) / 256, 256, 0, stream>>>(
            zbuf, feat[i], out + OOFF[i], total, 8);
      }
    }
  } else {
    __hip_bfloat16* Rbuf = R1;
    for (int i = 0; i < 5; ++i) {
      const int H = HS[i], W = H, HW = H * W, Hp = H + 2, Wp = W + 2;
      const int lw = 31 - __builtin_clz((unsigned)W);
      const float scl = 63.f / (float)(H - 1);
      wtrans_kernel<<<2048, 256, 0, stream>>>(cw, bng, bnb, bnm, bnv, Wt, biasW, i);
      const int ntiles = (HW + 127) / 128;
      for (int b0 = 0; b0 < 2; ++b0) {
        resize_kernel<<<dim3(8, Hp), 256, 0, stream>>>(
            attr + (size_t)b0 * 2048 * 4096, Rbuf, W, Hp, Wp, scl);
        conv_kernel<<<dim3(ntiles * 2, 1), 256, 0, stream>>>(
            Rbuf, Wt, biasW + i * 2048, attnW + i * 16,
            feat[i], out + OOFF[i], W, lw, Hp, Wp, HW, b0, 1, 8);
      }
    }
  }
}

// Round 17
// 706.441 us; speedup vs baseline: 1.0029x; 1.0029x over previous
//
#include <hip/hip_runtime.h>
#include <hip/hip_bf16.h>
#include <cstdint>

typedef __attribute__((ext_vector_type(8))) short short8;
typedef __attribute__((ext_vector_type(4))) float f32x4;

#define EPSV 1e-5f

// async global->LDS, 16B per lane; LDS dest = wave-uniform base + lane*16
__device__ __forceinline__ void gload_lds16(const void* g, void* l) {
  __builtin_amdgcn_global_load_lds(
      (const __attribute__((address_space(1))) void*)(uintptr_t)g,
      (__attribute__((address_space(3))) void*)(uint32_t)(uintptr_t)l,
      16, 0, 0);
}

__device__ __forceinline__ uint32_t f2bf_rne(float v) {
  const uint32_t u = __float_as_uint(v);
  const uint32_t r = ((u >> 16) & 1u) + 0x7fffu;
  return (u + r) >> 16;
}
__device__ __forceinline__ float bf2f(uint32_t u) {
  return __uint_as_float(u << 16);
}

// ---------------- spatial mean (attr): one block per channel ----------------
__global__ void mean_kernel(const float* __restrict__ in, float* __restrict__ out,
                            int HW, float inv) {
  const int ch = blockIdx.x;
  const int t = threadIdx.x;
  const float* p = in + (size_t)ch * HW;
  float s = 0.f;
  const int nv = HW >> 2;
  const float4* pv = (const float4*)p;
  for (int i = t; i < nv; i += 256) { float4 v = pv[i]; s += v.x + v.y + v.z + v.w; }
  __shared__ float red[256];
  red[t] = s; __syncthreads();
  for (int off = 128; off > 0; off >>= 1) {
    if (t < off) red[t] += red[t + off];
    __syncthreads();
  }
  if (t == 0) out[ch] = red[0] * inv;
}

// ---- fused feat means: all 5 scales in one launch (2560 blocks) ----
__global__ void meanf_kernel(const float* __restrict__ f0, const float* __restrict__ f1,
                             const float* __restrict__ f2, const float* __restrict__ f3,
                             const float* __restrict__ f4, float* __restrict__ out) {
  const int scale = blockIdx.x >> 9;
  const int ch = blockIdx.x & 511;
  const int t = threadIdx.x;
  const float* base;
  int HW;
  switch (scale) {
    case 0: base = f0; HW = 16384; break;
    case 1: base = f1; HW = 4096;  break;
    case 2: base = f2; HW = 1024;  break;
    case 3: base = f3; HW = 256;   break;
    default: base = f4; HW = 64;   break;
  }
  const float* p = base + (size_t)ch * HW;
  float s = 0.f;
  const int nv = HW >> 2;
  const float4* pv = (const float4*)p;
  for (int i = t; i < nv; i += 256) { float4 v = pv[i]; s += v.x + v.y + v.z + v.w; }
  __shared__ float red[256];
  red[t] = s; __syncthreads();
  for (int off = 128; off > 0; off >>= 1) {
    if (t < off) red[t] += red[t + off];
    __syncthreads();
  }
  if (t == 0) out[scale * 512 + ch] = red[0] / (float)HW;
}

// ------- fold BN into weights for ONE scale; layout [g][tap][co][ci] bf16 ----
__global__ void wtrans_kernel(const float* __restrict__ cw,
                              const float* __restrict__ gamma, const float* __restrict__ beta,
                              const float* __restrict__ mean, const float* __restrict__ var,
                              __hip_bfloat16* __restrict__ wt, float* __restrict__ bias,
                              int i) {
  __shared__ float wl[2304];
  const int oc = blockIdx.x;   // 0..2047
  const int t  = threadIdx.x;  // 0..255
  const int idx = i * 2048 + oc;
  const float* src = cw + (size_t)idx * 2304;
  for (int e = t; e < 2304; e += 256) wl[e] = src[e];
  __syncthreads();
  const float sc = rsqrtf(var[idx] + EPSV) * gamma[idx];
  if (t == 0) bias[idx] = beta[idx] - mean[idx] * sc;
  const int g = oc >> 8, co = oc & 255;
  const size_t dbase = (size_t)g * 9 * 65536 + co * 256 + t;
#pragma unroll
  for (int tap = 0; tap < 9; ++tap)
    wt[dbase + (size_t)tap * 65536] = __float2bfloat16(wl[t * 9 + tap] * sc);
}

// ------------- gating: MLPs + logits + softmax (1 block) -------------
__global__ void gate_kernel(const float* __restrict__ meanA, const float* __restrict__ meanF,
                            const float* __restrict__ Wa, const float* __restrict__ ba,
                            const float* __restrict__ Wf, const float* __restrict__ bfp,
                            float* __restrict__ attn) {
  __shared__ float mA[16 * 256];
  __shared__ float mF[10 * 256];
  __shared__ float pA[16 * 256];
  __shared__ float pF[10 * 256];
  __shared__ float lg[80];
  const int t = threadIdx.x;
  for (int i = t; i < 4096; i += 256) mA[i] = meanA[i];
  for (int i = t; i < 2560; i += 256) mF[i] = meanF[i];
  __syncthreads();
  {
    float acc[16];
#pragma unroll
    for (int j = 0; j < 16; ++j) acc[j] = 0.f;
    for (int ci = 0; ci < 256; ++ci) {
      const float w = Wa[t * 256 + ci];
#pragma unroll
      for (int j = 0; j < 16; ++j) acc[j] += mA[j * 256 + ci] * w;
    }
    const float bb = ba[t];
#pragma unroll
    for (int j = 0; j < 16; ++j) pA[j * 256 + t] = acc[j] + bb;
  }
  {
    float acc[10];
#pragma unroll
    for (int j = 0; j < 10; ++j) acc[j] = 0.f;
    for (int ci = 0; ci < 256; ++ci) {
      const float w = Wf[t * 256 + ci];
#pragma unroll
      for (int j = 0; j < 10; ++j) acc[j] += mF[j * 256 + ci] * w;
    }
    const float bb = bfp[t];
#pragma unroll
    for (int j = 0; j < 10; ++j) pF[j * 256 + t] = acc[j] + bb;
  }
  __syncthreads();
  if (t < 80) {
    const int i = t >> 4, r = t & 15, b = r >> 3, k = r & 7;
    const float* a = &pA[(b * 8 + k) * 256];
    const float* f = &pF[(i * 2 + b) * 256];
    float d = 0.f;
    for (int c = 0; c < 256; ++c) d += a[c] * f[c];
    lg[t] = d;
  }
  __syncthreads();
  if (t < 10) {
    const int base = t * 8;
    float m = lg[base];
    for (int k = 1; k < 8; ++k) m = fmaxf(m, lg[base + k]);
    float e[8], s = 0.f;
    for (int k = 0; k < 8; ++k) { e[k] = __expf(lg[base + k] - m); s += e[k]; }
    const float invs = 1.f / s;
    for (int k = 0; k < 8; ++k) attn[base + k] = e[k] * invs;
  }
}

// --- bilinear resize (align_corners) NCHW f32 -> padded NHWC bf16 ----
// Used for scale 1 (scl=1.0 -> exact bf16 NHWC conversion) and fallback path.
__global__ void resize_kernel(const float* __restrict__ attr,
                              __hip_bfloat16* __restrict__ R,
                              int W, int Hp, int Wp, float scl) {
  const int bk = blockIdx.x;   // bb*8+k
  const int yp = blockIdx.y;
  const int t  = threadIdx.x;
  const size_t rowbase = ((size_t)bk * Hp + yp) * (size_t)Wp * 256;
  if (yp == 0 || yp == Hp - 1) {
    uint32_t* p = (uint32_t*)(R + rowbase);
    const int n = Wp * 128;
    for (int idx = t; idx < n; idx += 256) p[idx] = 0u;
    return;
  }
  const int y = yp - 1;
  const float fy = y * scl;
  int y0 = (int)floorf(fy); if (y0 > 63) y0 = 63;
  const float wy = fy - (float)y0;
  const int y1 = min(y0 + 1, 63);
  __shared__ float buf[2][64][65];
  const int cc = t >> 2, seg = (t & 3) * 16;
  const int bb = bk >> 3, k = bk & 7;
  const float* ab = attr + (size_t)bb * 2048 * 4096;
  const int ci = t & 63;
  for (int cq = 0; cq < 4; ++cq) {
    __syncthreads();
    {
      const int ch = k * 256 + cq * 64 + cc;
      const float* r0 = ab + ((size_t)ch * 64 + y0) * 64;
      const float* r1 = ab + ((size_t)ch * 64 + y1) * 64;
#pragma unroll
      for (int u = 0; u < 4; ++u) {
        float4 v0 = ((const float4*)r0)[(t & 3) * 4 + u];
        float4 v1 = ((const float4*)r1)[(t & 3) * 4 + u];
        buf[0][cc][seg + u * 4 + 0] = v0.x; buf[0][cc][seg + u * 4 + 1] = v0.y;
        buf[0][cc][seg + u * 4 + 2] = v0.z; buf[0][cc][seg + u * 4 + 3] = v0.w;
        buf[1][cc][seg + u * 4 + 0] = v1.x; buf[1][cc][seg + u * 4 + 1] = v1.y;
        buf[1][cc][seg + u * 4 + 2] = v1.z; buf[1][cc][seg + u * 4 + 3] = v1.w;
      }
    }
    __syncthreads();
    for (int x = t >> 6; x < W; x += 4) {
      const float fx = x * scl;
      int x0 = (int)floorf(fx); if (x0 > 63) x0 = 63;
      const float wx = fx - (float)x0;
      const int x1 = min(x0 + 1, 63);
      const float top = buf[0][ci][x0] * (1.f - wx) + buf[0][ci][x1] * wx;
      const float bot = buf[1][ci][x0] * (1.f - wx) + buf[1][ci][x1] * wx;
      R[rowbase + (size_t)(x + 1) * 256 + cq * 64 + ci] = __float2bfloat16(top * (1.f - wy) + bot * wy);
    }
    if (t < 64) {
      R[rowbase + cq * 64 + t] = __float2bfloat16(0.f);
      R[rowbase + (size_t)(Wp - 1) * 256 + cq * 64 + t] = __float2bfloat16(0.f);
    }
  }
}

// ---- bilinear resize from R1 (scale-1 identity buffer, NHWC bf16 66x66 padded)
__global__ void resizeR1_kernel(const __hip_bfloat16* __restrict__ R1,
                                __hip_bfloat16* __restrict__ R,
                                int W, int Hp, int Wp, float scl) {
  const int bk = blockIdx.x;   // 0..15
  const int yp = blockIdx.y;
  const int t  = threadIdx.x;
  const size_t rowbase = ((size_t)bk * Hp + yp) * (size_t)Wp * 256;
  if (yp == 0 || yp == Hp - 1) {
    uint32_t* p = (uint32_t*)(R + rowbase);
    const int n = Wp * 128;
    for (int idx = t; idx < n; idx += 256) p[idx] = 0u;
    return;
  }
  const int y = yp - 1;
  const float fy = y * scl;
  int y0 = (int)floorf(fy); if (y0 > 63) y0 = 63;
  const float wy = fy - (float)y0;
  const int y1 = min(y0 + 1, 63);
  const __hip_bfloat16* r0 = R1 + ((size_t)bk * 66 + (y0 + 1)) * 66 * 256 + 256;
  const __hip_bfloat16* r1 = R1 + ((size_t)bk * 66 + (y1 + 1)) * 66 * 256 + 256;
  const int ci4 = (t & 63) * 4;
  for (int x = t >> 6; x < W; x += 4) {
    const float fx = x * scl;
    int x0 = (int)floorf(fx); if (x0 > 63) x0 = 63;
    const float wx = fx - (float)x0;
    const int x1 = min(x0 + 1, 63);
    const ushort4 a00 = *(const ushort4*)&r0[x0 * 256 + ci4];
    const ushort4 a01 = *(const ushort4*)&r0[x1 * 256 + ci4];
    const ushort4 a10 = *(const ushort4*)&r1[x0 * 256 + ci4];
    const ushort4 a11 = *(const ushort4*)&r1[x1 * 256 + ci4];
    short4 st;
    {
      const float t0 = bf2f(a00.x) * (1.f - wx) + bf2f(a01.x) * wx;
      const float b0 = bf2f(a10.x) * (1.f - wx) + bf2f(a11.x) * wx;
      st.x = (short)f2bf_rne(t0 * (1.f - wy) + b0 * wy);
      const float t1 = bf2f(a00.y) * (1.f - wx) + bf2f(a01.y) * wx;
      const float b1 = bf2f(a10.y) * (1.f - wx) + bf2f(a11.y) * wx;
      st.y = (short)f2bf_rne(t1 * (1.f - wy) + b1 * wy);
      const float t2 = bf2f(a00.z) * (1.f - wx) + bf2f(a01.z) * wx;
      const float b2 = bf2f(a10.z) * (1.f - wx) + bf2f(a11.z) * wx;
      st.z = (short)f2bf_rne(t2 * (1.f - wy) + b2 * wy);
      const float t3 = bf2f(a00.w) * (1.f - wx) + bf2f(a01.w) * wx;
      const float b3 = bf2f(a10.w) * (1.f - wx) + bf2f(a11.w) * wx;
      st.w = (short)f2bf_rne(t3 * (1.f - wy) + b3 * wy);
    }
    *(short4*)&R[rowbase + (size_t)(x + 1) * 256 + ci4] = st;
  }
  if (t < 64) {
    const short4 z4 = {0, 0, 0, 0};
    *(short4*)&R[rowbase + t * 4] = z4;
    *(short4*)&R[rowbase + (size_t)(Wp - 1) * 256 + t * 4] = z4;
  }
}

// stage index -> (g, ty, tx, cq)
__device__ __forceinline__ void coords36(int u, int g0, int& g, int& ty, int& tx, int& cq) {
  g = g0 + u / 36;
  const int r = u % 36;
  const int tap = r >> 2;
  cq = r & 3;
  ty = tap / 3;
  tx = tap - ty * 3;
}

// ============ conv256 (R8/R15 best-measured): 256co x 256sp, 8 waves ============
// fin packed bf16 (gcount groups folded in-register); 4 phases/K-tile with
// mid-K-tile prefetch of t+1; vmcnt(0) once per K-tile; XCD remap at 256 blks.
__global__ __launch_bounds__(512, 1)
void conv256_kernel(const __hip_bfloat16* __restrict__ R,
                    const __hip_bfloat16* __restrict__ Wt,   // [8][9][256][256]
                    const float* __restrict__ bias,          // [2048] this scale
                    const float* __restrict__ attn,          // [2][8] this scale
                    __hip_bfloat16* __restrict__ zout,
                    int W, int lw, int Hp, int Wp, int HW,
                    int NB, int gcount) {
  __shared__ alignas(16) __hip_bfloat16 ldsA[2][256 * 64];
  __shared__ alignas(16) __hip_bfloat16 ldsB[2][256 * 64];
  const int tid  = threadIdx.x;
  const int lane = tid & 63;
  const int wave = __builtin_amdgcn_readfirstlane(tid >> 6);
  const int wm = (wave >> 2) * 128;
  const int wn = (wave & 3) * 64;

  const int X = gridDim.x;
  int xp = blockIdx.x, yv = blockIdx.y;
  if (X * gridDim.y == 256) {
    const int lin2 = blockIdx.x + X * blockIdx.y;
    const int d = (lin2 & 7) * 32 + (lin2 >> 3);
    yv = d / X; xp = d - yv * X;
  }
  const int n0 = xp * 256;
  const int bb = yv % NB;
  const int gs = yv / NB;
  const int g0 = gs * gcount;

  const int c8 = lane & 7, r8 = lane >> 3;
  const int sc = (c8 ^ r8) << 3;
  const int aoff0 = ((wave * 32 + r8) << 8) + sc;
  const int dst0  = wave * 2048;
  int boff[4];
#pragma unroll
  for (int q = 0; q < 4; ++q) {
    const int row = wave * 32 + q * 8 + r8;
    const int sg = n0 + row;
    const int y = sg >> lw, x = sg & (W - 1);
    boff[q] = ((y * Wp + x) << 8) + sc;
  }

  const size_t rgstride = (size_t)Hp * Wp * 256;
  const __hip_bfloat16* Rb = R + (size_t)bb * 8 * rgstride;

  const f32x4 fz = {0.f, 0.f, 0.f, 0.f};
  f32x4 acc[8][4];
  uint32_t finp[8][4][2];
#pragma unroll
  for (int mf = 0; mf < 8; ++mf)
#pragma unroll
    for (int nf = 0; nf < 4; ++nf) {
      acc[mf][nf] = fz; finp[mf][nf][0] = 0u; finp[mf][nf][1] = 0u;
    }

  const int nk = gcount * 36;
  {
    const __hip_bfloat16* wp = Wt + ((size_t)g0 * 9 << 16);
    const __hip_bfloat16* rp = Rb + (size_t)g0 * rgstride;
#pragma unroll
    for (int q = 0; q < 4; ++q) gload_lds16(wp + aoff0 + q * 2048, &ldsA[0][dst0 + q * 512]);
#pragma unroll
    for (int q = 0; q < 4; ++q) gload_lds16(rp + boff[q], &ldsB[0][dst0 + q * 512]);
  }

  int foldc = 0, gcur = g0;
  for (int t = 0; t < nk; ++t) {
    const int c = t & 1;
    const bool pf = (t + 1 < nk);
    int g1, ty1, tx1, cq1;
    coords36(pf ? t + 1 : t, g0, g1, ty1, tx1, cq1);
    const __hip_bfloat16* wp1 = Wt + (((size_t)g1 * 9 + ty1 * 3 + tx1) << 16) + (cq1 << 6);
    const __hip_bfloat16* rp1 = Rb + (size_t)g1 * rgstride + ((ty1 * Wp + tx1) << 8) + (cq1 << 6);

    asm volatile("s_waitcnt vmcnt(0)" ::: "memory");
    __builtin_amdgcn_s_barrier();
    asm volatile("" ::: "memory");

    const __hip_bfloat16* pA = &ldsA[c][0];
    const __hip_bfloat16* pB = &ldsB[c][0];
    __hip_bfloat16* dA = &ldsA[c ^ 1][0];
    __hip_bfloat16* dB = &ldsB[c ^ 1][0];

#pragma unroll
    for (int ks = 0; ks < 2; ++ks) {
      const int cb = ks * 4 + (lane >> 4);
      short8 bfv[4];
#pragma unroll
      for (int nf = 0; nf < 4; ++nf) {
        const int row = wn + nf * 16 + (lane & 15);
        bfv[nf] = *(const short8*)&pB[(row << 6) + ((cb ^ (row & 7)) << 3)];
      }
#pragma unroll
      for (int h = 0; h < 2; ++h) {
        short8 af[4];
#pragma unroll
        for (int m = 0; m < 4; ++m) {
          const int row = wm + (h * 4 + m) * 16 + (lane & 15);
          af[m] = *(const short8*)&pA[(row << 6) + ((cb ^ (row & 7)) << 3)];
        }
        if (ks == 0 && pf) {
          if (h == 0) {
#pragma unroll
            for (int q = 0; q < 4; ++q) gload_lds16(wp1 + aoff0 + q * 2048, dA + dst0 + q * 512);
          } else {
#pragma unroll
            for (int q = 0; q < 4; ++q) gload_lds16(rp1 + boff[q], dB + dst0 + q * 512);
          }
        }
        __builtin_amdgcn_s_barrier();
        __builtin_amdgcn_sched_barrier(0);
        __builtin_amdgcn_s_setprio(1);
#pragma unroll
        for (int m = 0; m < 4; ++m)
#pragma unroll
          for (int nf = 0; nf < 4; ++nf)
            acc[h * 4 + m][nf] = __builtin_amdgcn_mfma_f32_16x16x32_bf16(
                af[m], bfv[nf], acc[h * 4 + m][nf], 0, 0, 0);
        __builtin_amdgcn_s_setprio(0);
        __builtin_amdgcn_s_barrier();
        asm volatile("" ::: "memory");
      }
    }

    if (++foldc == 36) {
      foldc = 0;
      const float aw = attn[bb * 8 + gcur];
#pragma unroll
      for (int mf = 0; mf < 8; ++mf) {
        const int cobase = wm + mf * 16 + ((lane >> 4) << 2);
#pragma unroll
        for (int pr = 0; pr < 2; ++pr) {
          const float b0v = bias[(gcur << 8) + cobase + pr * 2 + 0];
          const float b1v = bias[(gcur << 8) + cobase + pr * 2 + 1];
#pragma unroll
          for (int nf = 0; nf < 4; ++nf) {
            const uint32_t p = finp[mf][nf][pr];
            const float f0 = __uint_as_float(p << 16)
                           + aw * fmaxf(acc[mf][nf][pr * 2 + 0] + b0v, 0.f);
            const float f1 = __uint_as_float(p & 0xffff0000u)
                           + aw * fmaxf(acc[mf][nf][pr * 2 + 1] + b1v, 0.f);
            finp[mf][nf][pr] = (f2bf_rne(f1) << 16) | f2bf_rne(f0);
          }
        }
#pragma unroll
        for (int nf = 0; nf < 4; ++nf) acc[mf][nf] = fz;
      }
      ++gcur;
    }
  }

  __hip_bfloat16* zb = zout + (size_t)(gs * 2 + bb) * 256 * (size_t)HW;
#pragma unroll
  for (int mf = 0; mf < 8; ++mf) {
    const int cobase = wm + mf * 16 + ((lane >> 4) << 2);
#pragma unroll
    for (int nf = 0; nf < 4; ++nf) {
      const int n = n0 + wn + nf * 16 + (lane & 15);
#pragma unroll
      for (int pr = 0; pr < 2; ++pr) {
        const uint32_t p = finp[mf][nf][pr];
        zb[(size_t)(cobase + pr * 2 + 0) * HW + n] =
            __float2bfloat16(__uint_as_float(p << 16));
        zb[(size_t)(cobase + pr * 2 + 1) * HW + n] =
            __float2bfloat16(__uint_as_float(p & 0xffff0000u));
      }
    }
  }
}

// -------- 128x128 conv (scales 2-4 + fallback), R15 unchanged ---------
__global__ __launch_bounds__(256, 2)
void conv_kernel(const __hip_bfloat16* __restrict__ R,
                 const __hip_bfloat16* __restrict__ Wt,
                 const float* __restrict__ bias,
                 const float* __restrict__ attn,
                 const float* __restrict__ featp,
                 void* __restrict__ outp,
                 int W, int lw, int Hp, int Wp, int HW,
                 int b0, int NB, int gcount) {
  __shared__ alignas(16) __hip_bfloat16 ldsA[2][128 * 64];
  __shared__ alignas(16) __hip_bfloat16 ldsB[3][128 * 64];
  const int tid  = threadIdx.x;
  const int lane = tid & 63;
  const int wave = __builtin_amdgcn_readfirstlane(tid >> 6);
  const int wm = (wave >> 1) * 64;
  const int wn = (wave & 1) * 64;

  const int nx  = gridDim.x;
  const int lin = blockIdx.x;
  const int pos = ((nx & 7) == 0) ? ((lin & 7) * (nx >> 3) + (lin >> 3)) : lin;
  const int co0 = (pos & 1) * 128;
  const int n0  = (pos >> 1) * 128;

  const int bb  = (int)blockIdx.y % NB;
  const int gs  = (int)blockIdx.y / NB;
  const int b   = b0 + bb;
  const int g0  = gs * gcount;

  const int c8 = lane & 7;
  const int r8 = lane >> 3;
  int aoff[4], boff[4], dst[4];
#pragma unroll
  for (int q = 0; q < 4; ++q) {
    const int row = (wave * 4 + q) * 8 + r8;
    const int sc = (c8 ^ (row & 7)) << 3;
    aoff[q] = ((co0 + row) << 8) + sc;
    int sg = n0 + row; if (sg >= HW) sg = HW - 1;
    const int y = sg >> lw, x = sg & (W - 1);
    boff[q] = ((y * Wp + x) << 8) + sc;
    dst[q] = (wave * 4 + q) * 512;
  }

  const size_t rgstride = (size_t)Hp * Wp * 256;
  const __hip_bfloat16* Rb = R + (size_t)bb * 8 * rgstride;

  const f32x4 fz = {0.f, 0.f, 0.f, 0.f};
  f32x4 fin[4][4], acc[4][4];
#pragma unroll
  for (int mf = 0; mf < 4; ++mf)
#pragma unroll
    for (int nf = 0; nf < 4; ++nf) { fin[mf][nf] = fz; acc[mf][nf] = fz; }

  const int nstages = gcount * 36;
  {
    int g, ty, tx, cq;
    coords36(0, g0, g, ty, tx, cq);
    const __hip_bfloat16* wp = Wt + (((size_t)g * 9 + ty * 3 + tx) << 16) + (cq << 6);
    const __hip_bfloat16* rp = Rb + (size_t)g * rgstride + ((ty * Wp + tx) << 8) + (cq << 6);
#pragma unroll
    for (int q = 0; q < 4; ++q) gload_lds16(wp + aoff[q], &ldsA[0][dst[q]]);
#pragma unroll
    for (int q = 0; q < 4; ++q) gload_lds16(rp + boff[q], &ldsB[0][dst[q]]);
    coords36(1 < nstages ? 1 : 0, g0, g, ty, tx, cq);
    const __hip_bfloat16* rp1 = Rb + (size_t)g * rgstride + ((ty * Wp + tx) << 8) + (cq << 6);
#pragma unroll
    for (int q = 0; q < 4; ++q) gload_lds16(rp1 + boff[q], &ldsB[1][dst[q]]);
  }

  int bcur = 0, b2 = 2;
  int foldc = 0, gcur = g0;

  for (int s = 0; s < nstages; ++s) {
    __builtin_amdgcn_s_barrier();
    asm volatile("" ::: "memory");
    if (s + 1 < nstages) {
      int g, ty, tx, cq;
      coords36(s + 1, g0, g, ty, tx, cq);
      const __hip_bfloat16* wp = Wt + (((size_t)g * 9 + ty * 3 + tx) << 16) + (cq << 6);
      __hip_bfloat16* dA = &ldsA[(s + 1) & 1][0];
#pragma unroll
      for (int q = 0; q < 4; ++q) gload_lds16(wp + aoff[q], dA + dst[q]);
    }
    if (s + 2 < nstages) {
      int g, ty, tx, cq;
      coords36(s + 2, g0, g, ty, tx, cq);
      const __hip_bfloat16* rp = Rb + (size_t)g * rgstride + ((ty * Wp + tx) << 8) + (cq << 6);
      __hip_bfloat16* dB = &ldsB[b2][0];
#pragma unroll
      for (int q = 0; q < 4; ++q) gload_lds16(rp + boff[q], dB + dst[q]);
    }
    if (s + 2 < nstages)      asm volatile("s_waitcnt vmcnt(12)" ::: "memory");
    else if (s + 1 < nstages) asm volatile("s_waitcnt vmcnt(8)" ::: "memory");
    else                      asm volatile("s_waitcnt vmcnt(0)" ::: "memory");
    __builtin_amdgcn_s_barrier();
    asm volatile("" ::: "memory");

    const __hip_bfloat16* pA = &ldsA[s & 1][0];
    const __hip_bfloat16* pB = &ldsB[bcur][0];
#pragma unroll
    for (int ks = 0; ks < 2; ++ks) {
      short8 af[4], bfv[4];
      const int cb = ks * 4 + (lane >> 4);
#pragma unroll
      for (int mf = 0; mf < 4; ++mf) {
        const int row = wm + mf * 16 + (lane & 15);
        af[mf] = *(const short8*)&pA[(row << 6) + ((cb ^ (row & 7)) << 3)];
      }
#pragma unroll
      for (int nf = 0; nf < 4; ++nf) {
        const int row = wn + nf * 16 + (lane & 15);
        bfv[nf] = *(const short8*)&pB[(row << 6) + ((cb ^ (row & 7)) << 3)];
      }
#pragma unroll
      for (int mf = 0; mf < 4; ++mf)
#pragma unroll
        for (int nf = 0; nf < 4; ++nf)
          acc[mf][nf] = __builtin_amdgcn_mfma_f32_16x16x32_bf16(
              af[mf], bfv[nf], acc[mf][nf], 0, 0, 0);
    }

    if (++bcur == 3) bcur = 0;
    if (++b2 == 3) b2 = 0;

    if (++foldc == 36) {
      foldc = 0;
      const float aw = attn[b * 8 + gcur];
#pragma unroll
      for (int mf = 0; mf < 4; ++mf) {
        const int cobase = co0 + wm + mf * 16 + ((lane >> 4) << 2);
#pragma unroll
        for (int r = 0; r < 4; ++r) {
          const float bs = bias[(gcur << 8) + cobase + r];
#pragma unroll
          for (int nf = 0; nf < 4; ++nf) {
            fin[mf][nf][r] += aw * fmaxf(acc[mf][nf][r] + bs, 0.f);
            acc[mf][nf][r] = 0.f;
          }
        }
      }
      ++gcur;
    }
  }

  const size_t plane = (size_t)256 * HW;
  if (featp) {
    const float* fb = featp + (size_t)b * plane;
    float* ob = (float*)outp + (size_t)b * plane;
#pragma unroll
    for (int mf = 0; mf < 4; ++mf) {
      const int cobase = co0 + wm + mf * 16 + ((lane >> 4) << 2);
#pragma unroll
      for (int nf = 0; nf < 4; ++nf) {
        const int n = n0 + wn + nf * 16 + (lane & 15);
        if (n < HW) {
#pragma unroll
          for (int r = 0; r < 4; ++r) {
            const size_t idx = (size_t)(cobase + r) * HW + n;
            ob[idx] = fmaxf(fb[idx] + fin[mf][nf][r], 0.f);
          }
        }
      }
    }
  } else {
    __hip_bfloat16* zb = (__hip_bfloat16*)outp + ((size_t)gs * 2 + b) * plane;
#pragma unroll
    for (int mf = 0; mf < 4; ++mf) {
      const int cobase = co0 + wm + mf * 16 + ((lane >> 4) << 2);
#pragma unroll
      for (int nf = 0; nf < 4; ++nf) {
        const int n = n0 + wn + nf * 16 + (lane & 15);
        if (n < HW) {
#pragma unroll
          for (int r = 0; r < 4; ++r)
            zb[(size_t)(cobase + r) * HW + n] = __float2bfloat16(fin[mf][nf][r]);
        }
      }
    }
  }
}

// ---- combine bf16 partials: out = relu(feat + sum_s z[s]) ----
__global__ void reduce_kernel(const __hip_bfloat16* __restrict__ z,
                              const float* __restrict__ feat,
                              float* __restrict__ outp, int total, int S) {
  const int i4 = (blockIdx.x * 256 + threadIdx.x) * 4;
  if (i4 >= total) return;
  float4 f = *(const float4*)(feat + i4);
  float s0 = f.x, s1 = f.y, s2 = f.z, s3 = f.w;
  for (int j = 0; j < S; ++j) {
    const ushort4 v = *(const ushort4*)(z + (size_t)j * total + i4);
    s0 += bf2f(v.x);
    s1 += bf2f(v.y);
    s2 += bf2f(v.z);
    s3 += bf2f(v.w);
  }
  float4 o = {fmaxf(s0, 0.f), fmaxf(s1, 0.f), fmaxf(s2, 0.f), fmaxf(s3, 0.f)};
  *(float4*)(outp + i4) = o;
}

extern "C" void kernel_launch(void* const* d_in, const int* in_sizes, int n_in,
                              void* d_out, int out_size, void* d_ws, size_t ws_size,
                              hipStream_t stream) {
  const float* feat[5];
  for (int i = 0; i < 5; ++i) feat[i] = (const float*)d_in[i];
  const float* attr = (const float*)d_in[5];
  const float* mfw = (const float*)d_in[6];
  const float* mfb = (const float*)d_in[7];
  const float* maw = (const float*)d_in[8];
  const float* mab = (const float*)d_in[9];
  const float* cw  = (const float*)d_in[10];
  const float* bng = (const float*)d_in[11];
  const float* bnb = (const float*)d_in[12];
  const float* bnm = (const float*)d_in[13];
  const float* bnv = (const float*)d_in[14];
  float* out = (float*)d_out;

  char* ws = (char*)d_ws;
  float* attnW = (float*)(ws);
  float* meanA = (float*)(ws + 512);
  float* meanF = (float*)(ws + 20480);
  float* biasW = (float*)(ws + 32768);
  __hip_bfloat16* Wt  = (__hip_bfloat16*)(ws + 131072);
  __hip_bfloat16* R1  = (__hip_bfloat16*)(ws + 9568256);
  __hip_bfloat16* R0  = (__hip_bfloat16*)(ws + 45252608);
  __hip_bfloat16* zbuf = (__hip_bfloat16*)(ws + 183697408);

  const bool full = ws_size >= (size_t)217251840;

  static const int HS[5] = {128, 64, 32, 16, 8};
  static const size_t OOFF[5] = {0, 8388608, 10485760, 11010048, 11141120};
  static const int ORDER[5] = {1, 0, 2, 3, 4};

  mean_kernel<<<4096, 256, 0, stream>>>(attr, meanA, 4096, 1.f / 4096.f);
  meanf_kernel<<<2560, 256, 0, stream>>>(feat[0], feat[1], feat[2], feat[3], feat[4], meanF);
  gate_kernel<<<1, 256, 0, stream>>>(meanA, meanF, maw, mab, mfw, mfb, attnW);

  if (full) {
    for (int oi = 0; oi < 5; ++oi) {
      const int i = ORDER[oi];
      const int H = HS[i], W = H, HW = H * W, Hp = H + 2, Wp = W + 2;
      const int lw = 31 - __builtin_clz((unsigned)W);
      const float scl = 63.f / (float)(H - 1);
      __hip_bfloat16* Ri = (i == 1) ? R1 : R0;

      wtrans_kernel<<<2048, 256, 0, stream>>>(cw, bng, bnb, bnm, bnv, Wt, biasW, i);
      if (i == 1)
        resize_kernel<<<dim3(16, Hp), 256, 0, stream>>>(attr, R1, W, Hp, Wp, scl);
      else
        resizeR1_kernel<<<dim3(16, Hp), 256, 0, stream>>>(R1, Ri, W, Hp, Wp, scl);

      if (i <= 1) {
        const int S = (i == 0) ? 2 : 8;
        const int gcount = 8 / S;
        conv256_kernel<<<dim3(HW / 256, 2 * S), 512, 0, stream>>>(
            Ri, Wt, biasW + i * 2048, attnW + i * 16,
            zbuf, W, lw, Hp, Wp, HW, 2, gcount);
        const int total = 2 * 256 * HW;
        reduce_kernel<<<(total / 4 + 255) / 256, 256, 0, stream>>>(
            zbuf, feat[i], out + OOFF[i], total, S);
      } else {
        const int ntiles = (HW + 127) / 128;
        conv_kernel<<<dim3(ntiles * 2, 16), 256, 0, stream>>>(
            Ri, Wt, biasW + i * 2048, attnW + i * 16,
            nullptr, zbuf, W, lw, Hp, Wp, HW, 0, 2, 1);
        const int total = 2 * 256 * HW;
        reduce_kernel<<<(total / 4 + 255) / 256, 256, 0, stream>>>(
            zbuf, feat[i], out + OOFF[i], total, 8);
      }
    }
  } else {
    __hip_bfloat16* Rbuf = R1;
    for (int i = 0; i < 5; ++i) {
      const int H = HS[i], W = H, HW = H * W, Hp = H + 2, Wp = W + 2;
      const int lw = 31 - __builtin_clz((unsigned)W);
      const float scl = 63.f / (float)(H - 1);
      wtrans_kernel<<<2048, 256, 0, stream>>>(cw, bng, bnb, bnm, bnv, Wt, biasW, i);
      const int ntiles = (HW + 127) / 128;
      for (int b0 = 0; b0 < 2; ++b0) {
        resize_kernel<<<dim3(8, Hp), 256, 0, stream>>>(
            attr + (size_t)b0 * 2048 * 4096, Rbuf, W, Hp, Wp, scl);
        conv_kernel<<<dim3(ntiles * 2, 1), 256, 0, stream>>>(
            Rbuf, Wt, biasW + i * 2048, attnW + i * 16,
            feat[i], out + OOFF[i], W, lw, Hp, Wp, HW, b0, 1, 8);
      }
    }
  }
}